// Round 8
// baseline (68.234 us; speedup 1.0000x reference)
//
#include <hip/hip_runtime.h>
#include <hip/hip_bf16.h>

typedef unsigned short u16;
typedef unsigned int u32;
typedef __attribute__((ext_vector_type(8))) short bf16x8;
typedef __attribute__((ext_vector_type(16))) float f32x16;

#define S_LEN 2048
#define NHQ   16
#define NHKV  4
#define HD    64
#define KVBLK 64
#define LPAD  72          // 144B row stride
#define KVSTR (NHKV*HD)   // 256
#define QSTR  (NHQ*HD)    // 1024
// (1/sqrt(64)) * log2(e): scores land in exp2 domain
#define QSCALE 0.18033688011112042f
#define DEFER_THR 8.0f

__device__ __forceinline__ u32 cvt2(float lo, float hi) {
    __hip_bfloat162 hh = __float22bfloat162_rn(make_float2(lo, hi));
    union { __hip_bfloat162 h; u32 u; } c; c.h = hh; return c.u;   // v_cvt_pk_bf16_f32
}
__device__ __forceinline__ u16 cvt1(float x) {
    __hip_bfloat16 hh = __float2bfloat16(x);
    union { __hip_bfloat16 h; u16 u; } c; c.h = hh; return c.u;
}

__global__ __launch_bounds__(256, 2)
void gqa_fwd_kernel(const float* __restrict__ Qp, const float* __restrict__ Kp,
                    const float* __restrict__ Vp, float* __restrict__ Op)
{
    __shared__ __align__(16) u16 Kl[2][KVBLK][LPAD];  // K dbuf, [kv][d]
    __shared__ __align__(16) u16 Vt[2][HD][LPAD];     // V dbuf, transposed [dv][kv]

    const int tid  = threadIdx.x;
    const int w    = tid >> 6;         // 0..3, one wave per SIMD
    const int lane = tid & 63;
    const int q31  = lane & 31;
    const int h    = lane >> 5;        // lane half

    // 512 blocks = 32 heads x 16 q-tiles of 128 rows. qt strictly descending
    // (LPT / big-first): 2 blocks co-resident per CU pair big+small work.
    const int bid  = blockIdx.x;
    const int head = bid & 31;
    const int qt   = 15 - (bid >> 5);
    const int kvh  = head & 3;
    const int b    = (head >> 2) & 1;
    const int qh   = kvh * 4 + (head >> 3);

    const int qrow  = qt*128 + w*32 + q31;     // this lane's q row
    const int nt    = 2*qt + 1;                // staged kv tiles 0..nt
    const int tlast = 2*qt + (w >> 1);         // this wave's diagonal tile
    const int qcmp  = q31 + 32*(w & 1);        // mask kvl > qcmp at t==tlast

    const float* Kbase = Kp + (size_t)b * S_LEN * KVSTR + kvh*HD;
    const float* Vbase = Vp + (size_t)b * S_LEN * KVSTR + kvh*HD;
    const float* qp    = Qp + ((size_t)b * S_LEN + qrow) * QSTR + qh*HD;
    float*       ob    = Op + ((size_t)(b*NHQ + qh) * S_LEN + qrow) * HD;

    // staging maps (256 threads, one 64x64 tile each of K and V, 16 elems/thread):
    // K row-major b128 stores; V transposed contiguous scalar b16 stores.
    const int krow = tid >> 2;           // 0..63
    const int kd   = (tid & 3) * 16;     // 0,16,32,48
    const int vrow = tid & 63;           // kv
    const int vd0  = (tid >> 6) * 16;    // 0,16,32,48

    // ---- Q fragments (B operand of swapped QK^T): B[k=ks*16+h*8+i][q=q31] ----
    bf16x8 qf[4];
    #pragma unroll
    for (int ks = 0; ks < 4; ++ks) {
        const int d = ks*16 + h*8;
        const float4 x = *(const float4*)(qp + d);
        const float4 y = *(const float4*)(qp + d + 4);
        union { u32 u[4]; bf16x8 v; } t;
        t.u[0] = cvt2(x.x*QSCALE, x.y*QSCALE);
        t.u[1] = cvt2(x.z*QSCALE, x.w*QSCALE);
        t.u[2] = cvt2(y.x*QSCALE, y.y*QSCALE);
        t.u[3] = cvt2(y.z*QSCALE, y.w*QSCALE);
        qf[ks] = t.v;
    }

    // O^T accumulators: oacc{0,1}[rg] = O[q=q31][dv = set*32 + (rg&3)+8*(rg>>2)+4h]
    f32x16 oacc0, oacc1;
    #pragma unroll
    for (int i = 0; i < 16; ++i) { oacc0[i] = 0.f; oacc1[i] = 0.f; }
    float m_s = -1e30f;   // running max for q row (synced across lane halves)
    float l_p = 0.f;      // per-half partial row-sum; reduced in epilogue

    // ---- prologue: stage tile 0 into buf 0 ----
    {
        const float* kp0 = Kbase + (size_t)krow*KVSTR + kd;
        const float* vp0 = Vbase + (size_t)vrow*KVSTR + vd0;
        #pragma unroll
        for (int ii = 0; ii < 2; ++ii) {
            const float4 kx = *(const float4*)(kp0 + 8*ii);
            const float4 ky = *(const float4*)(kp0 + 8*ii + 4);
            *(uint4*)(&Kl[0][krow][kd + 8*ii]) = make_uint4(
                cvt2(kx.x,kx.y), cvt2(kx.z,kx.w), cvt2(ky.x,ky.y), cvt2(ky.z,ky.w));
        }
        #pragma unroll
        for (int ii = 0; ii < 4; ++ii) {
            const float4 vx = *(const float4*)(vp0 + 4*ii);
            Vt[0][vd0+4*ii+0][vrow] = cvt1(vx.x);
            Vt[0][vd0+4*ii+1][vrow] = cvt1(vx.y);
            Vt[0][vd0+4*ii+2][vrow] = cvt1(vx.z);
            Vt[0][vd0+4*ii+3][vrow] = cvt1(vx.w);
        }
    }
    __syncthreads();

    const float* kpt = Kbase + (size_t)(KVBLK + krow)*KVSTR + kd;
    const float* vpt = Vbase + (size_t)(KVBLK + vrow)*KVSTR + vd0;
    int cur = 0;

    for (int t = 0; t <= nt; ++t) {
        const bool pf_on = (t < nt);

        // ---- issue global prefetch for tile t+1 (consumed after compute) ----
        float4 kpf[4], vpf[4];
        if (pf_on) {
            #pragma unroll
            for (int ii = 0; ii < 4; ++ii) {
                kpf[ii] = *(const float4*)(kpt + 4*ii);
                vpf[ii] = *(const float4*)(vpt + 4*ii);
            }
        }
        // pin the prefetch issue point: loads may not sink into the staging section
        asm volatile("" ::: "memory");

        if (t <= tlast) {
            // ---- swapped QK^T (32x32x16): s{set}[rg] = S[kv=set*32+(rg&3)+8*(rg>>2)+4h][q=q31]
            f32x16 s0, s1;
            #pragma unroll
            for (int i = 0; i < 16; ++i) { s0[i] = 0.f; s1[i] = 0.f; }
            __builtin_amdgcn_s_setprio(1);
            #pragma unroll
            for (int ks = 0; ks < 4; ++ks) {
                bf16x8 k0 = *(const bf16x8*)(&Kl[cur][q31][ks*16 + h*8]);
                bf16x8 k1 = *(const bf16x8*)(&Kl[cur][32 + q31][ks*16 + h*8]);
                s0 = __builtin_amdgcn_mfma_f32_32x32x16_bf16(k0, qf[ks], s0, 0, 0, 0);
                s1 = __builtin_amdgcn_mfma_f32_32x32x16_bf16(k1, qf[ks], s1, 0, 0, 0);
            }
            __builtin_amdgcn_s_setprio(0);

            // ---- causal mask on this wave's diagonal tile ----
            if (t == tlast) {
                #pragma unroll
                for (int rg = 0; rg < 16; ++rg) {
                    const int kvl = (rg & 3) + 8*(rg >> 2) + 4*h;
                    if (kvl > qcmp)      s0[rg] = -1e30f;
                    if (kvl + 32 > qcmp) s1[rg] = -1e30f;
                }
            }

            // ---- local max over the lane's 32 scores (tree) ----
            float mx[8];
            #pragma unroll
            for (int i = 0; i < 8; ++i)
                mx[i] = fmaxf(fmaxf(s0[i], s0[i+8]), fmaxf(s1[i], s1[i+8]));
            const float lmax = fmaxf(fmaxf(fmaxf(mx[0],mx[1]), fmaxf(mx[2],mx[3])),
                                     fmaxf(fmaxf(mx[4],mx[5]), fmaxf(mx[6],mx[7])));

            // ---- T13 defer-max: reduce+rescale only when the max grew ----
            if (!__all(lmax <= m_s + DEFER_THR)) {
                float rmax = fmaxf(lmax, __shfl_xor(lmax, 32));
                const float mnew = fmaxf(m_s, rmax);
                const float cf   = __builtin_amdgcn_exp2f(m_s - mnew);
                m_s = mnew;
                l_p *= cf;
                #pragma unroll
                for (int i = 0; i < 16; ++i) { oacc0[i] *= cf; oacc1[i] *= cf; }
            }

            // ---- exp2 + partial sums ----
            float ps0 = 0.f, ps1 = 0.f;
            #pragma unroll
            for (int rg = 0; rg < 16; ++rg) {
                const float p0 = __builtin_amdgcn_exp2f(s0[rg] - m_s);
                const float p1 = __builtin_amdgcn_exp2f(s1[rg] - m_s);
                s0[rg] = p0; ps0 += p0;
                s1[rg] = p1; ps1 += p1;
            }
            l_p += ps0 + ps1;

            // ---- T12: P -> B-operand entirely in registers ----
            u32 Aw[8], Bw[8];
            #pragma unroll
            for (int m = 0; m < 4; ++m) {
                Aw[m]   = cvt2(s0[m*4+0], s0[m*4+1]);
                Bw[m]   = cvt2(s0[m*4+2], s0[m*4+3]);
                Aw[4+m] = cvt2(s1[m*4+0], s1[m*4+1]);
                Bw[4+m] = cvt2(s1[m*4+2], s1[m*4+3]);
            }

            // ---- O^T += V^T P : per c, frag words via permlane32_swap ----
            __builtin_amdgcn_s_setprio(1);
            #pragma unroll
            for (int c = 0; c < 4; ++c) {
                u32 w0 = Aw[2*c], w2 = Aw[2*c+1];
                u32 w1 = Bw[2*c], w3 = Bw[2*c+1];
                asm("v_permlane32_swap_b32 %0, %1" : "+v"(w0), "+v"(w2));
                asm("v_permlane32_swap_b32 %0, %1" : "+v"(w1), "+v"(w3));
                union { u32 u[4]; bf16x8 v; } pu;
                pu.u[0] = w0; pu.u[1] = w1; pu.u[2] = w2; pu.u[3] = w3;
                bf16x8 v0 = *(const bf16x8*)(&Vt[cur][q31][c*16 + h*8]);
                bf16x8 v1 = *(const bf16x8*)(&Vt[cur][32 + q31][c*16 + h*8]);
                oacc0 = __builtin_amdgcn_mfma_f32_32x32x16_bf16(v0, pu.v, oacc0, 0, 0, 0);
                oacc1 = __builtin_amdgcn_mfma_f32_32x32x16_bf16(v1, pu.v, oacc1, 0, 0, 0);
            }
            __builtin_amdgcn_s_setprio(0);
        }

        // ---- write prefetched tile to the other buffer; one barrier/tile ----
        if (pf_on) {
            #pragma unroll
            for (int ii = 0; ii < 2; ++ii) {
                *(uint4*)(&Kl[cur^1][krow][kd + 8*ii]) = make_uint4(
                    cvt2(kpf[2*ii].x, kpf[2*ii].y),   cvt2(kpf[2*ii].z, kpf[2*ii].w),
                    cvt2(kpf[2*ii+1].x, kpf[2*ii+1].y), cvt2(kpf[2*ii+1].z, kpf[2*ii+1].w));
            }
            #pragma unroll
            for (int ii = 0; ii < 4; ++ii) {
                Vt[cur^1][vd0+4*ii+0][vrow] = cvt1(vpf[ii].x);
                Vt[cur^1][vd0+4*ii+1][vrow] = cvt1(vpf[ii].y);
                Vt[cur^1][vd0+4*ii+2][vrow] = cvt1(vpf[ii].z);
                Vt[cur^1][vd0+4*ii+3][vrow] = cvt1(vpf[ii].w);
            }
            kpt += (size_t)KVBLK * KVSTR;
            vpt += (size_t)KVBLK * KVSTR;
            __syncthreads();
            cur ^= 1;
        }
    }

    // ---- epilogue: combine halves' l, normalize, store O^T (float4) ----
    l_p += __shfl_xor(l_p, 32);
    const float inv = 1.0f / l_p;
    #pragma unroll
    for (int k = 0; k < 4; ++k) {
        float4 o;
        o.x = oacc0[4*k+0]*inv; o.y = oacc0[4*k+1]*inv;
        o.z = oacc0[4*k+2]*inv; o.w = oacc0[4*k+3]*inv;
        *(float4*)(ob + 8*k + 4*h) = o;
        o.x = oacc1[4*k+0]*inv; o.y = oacc1[4*k+1]*inv;
        o.z = oacc1[4*k+2]*inv; o.w = oacc1[4*k+3]*inv;
        *(float4*)(ob + 32 + 8*k + 4*h) = o;
    }
}

extern "C" void kernel_launch(void* const* d_in, const int* in_sizes, int n_in,
                              void* d_out, int out_size, void* d_ws, size_t ws_size,
                              hipStream_t stream) {
    const float* Q = (const float*)d_in[0];
    const float* K = (const float*)d_in[1];
    const float* V = (const float*)d_in[2];
    // d_in[3] (tril mask) computed analytically, never read.
    float* O = (float*)d_out;
    gqa_fwd_kernel<<<dim3(512), dim3(256), 0, stream>>>(Q, K, V, O);
}

// Round 9
// 49.425 us; speedup vs baseline: 1.3805x; 1.3805x over previous
//
#include <hip/hip_runtime.h>
#include <hip/hip_bf16.h>

typedef unsigned short u16;
typedef unsigned int u32;
typedef __attribute__((ext_vector_type(8))) short bf16x8;
typedef __attribute__((ext_vector_type(16))) float f32x16;

#define S_LEN 2048
#define NHQ   16
#define NHKV  4
#define HD    64
#define KVBLK 64
#define LPAD  72          // K/V LDS row stride (u16)
#define MOPAD 68          // merge buffer row stride (f32), 272B = 16B-aligned
#define KVSTR (NHKV*HD)   // 256
#define QSTR  (NHQ*HD)    // 1024
// (1/sqrt(64)) * log2(e): scores land in exp2 domain
#define QSCALE 0.18033688011112042f
#define DEFER_THR 8.0f

__device__ __forceinline__ u32 cvt2(float lo, float hi) {
    __hip_bfloat162 hh = __float22bfloat162_rn(make_float2(lo, hi));
    union { __hip_bfloat162 h; u32 u; } c; c.h = hh; return c.u;   // v_cvt_pk_bf16_f32
}
__device__ __forceinline__ u16 cvt1(float x) {
    __hip_bfloat16 hh = __float2bfloat16(x);
    union { __hip_bfloat16 h; u16 u; } c; c.h = hh; return c.u;
}

__global__ __launch_bounds__(512, 2)
void gqa_fwd_kernel(const float* __restrict__ Qp, const float* __restrict__ Kp,
                    const float* __restrict__ Vp, float* __restrict__ Op)
{
    __shared__ __align__(16) u16 Kl[2][KVBLK][LPAD];   // K dbuf [kv][d]
    __shared__ __align__(16) u16 Vt[2][HD][LPAD];      // V dbuf transposed [dv][kv]
    __shared__ __align__(16) float Mo[4][32][MOPAD];   // pass-merge O buffer
    __shared__ float Mm[4][32], Ml[4][32];             // pass-merge m, l

    const int tid  = threadIdx.x;
    const int w    = tid >> 6;
    const int lane = tid & 63;
    const int q31  = lane & 31;
    const int h    = lane >> 5;

    // parity groups: g = popc(w)&1 puts one g=0 and one g=1 wave on every SIMD
    // under either wave->SIMD mapping (w%4 or w/2). rg = w>>1 is the unique
    // row-group 0..3 within each group. Group g computes kv-tiles of parity g
    // and stages them (LDS-write t+1, global-issue t+3) during its off-slots.
    const int g   = __popc(w) & 1;
    const int rg  = w >> 1;
    const int sid = rg * 64 + lane;   // staging index within the 4-wave group

    const int bid  = blockIdx.x;
    const int head = bid & 31;        // bid&7 spans (kvh,b): XCD L2 stream locality
    const int j    = bid >> 5;        // pass pair {15-j, j}: uniform 36 slots/block
    const int kvh  = head & 3;
    const int b    = (head >> 2) & 1;
    const int qh   = kvh * 4 + (head >> 3);

    const float* Kbase = Kp + (size_t)b * S_LEN * KVSTR + kvh*HD;
    const float* Vbase = Vp + (size_t)b * S_LEN * KVSTR + kvh*HD;
    const float* Qhead = Qp + (size_t)b * S_LEN * QSTR + qh*HD;
    float*       Ohead = Op + (size_t)(b*NHQ + qh) * S_LEN * HD;

    // staging maps (256 threads per group stage one 64x64 K + V tile)
    const int krow = sid >> 2;            // 0..63
    const int kd   = (sid & 3) * 16;      // 0,16,32,48
    const int vrow = sid & 63;            // kv
    const int vd0  = (sid >> 6) * 16;     // 0,16,32,48

    float4 kpf[4], vpf[4];   // in-flight staging registers (held across slots)

    auto ISSUE = [&](int tt) {
        const float* kp = Kbase + (size_t)(tt*KVBLK + krow)*KVSTR + kd;
        const float* vp = Vbase + (size_t)(tt*KVBLK + vrow)*KVSTR + vd0;
        kpf[0] = *(const float4*)(kp);
        kpf[1] = *(const float4*)(kp + 4);
        kpf[2] = *(const float4*)(kp + 8);
        kpf[3] = *(const float4*)(kp + 12);
        vpf[0] = *(const float4*)(vp);
        vpf[1] = *(const float4*)(vp + 4);
        vpf[2] = *(const float4*)(vp + 8);
        vpf[3] = *(const float4*)(vp + 12);
        asm volatile("" ::: "memory");   // pin issue point: no sinking to the use
    };
    auto WRITE = [&](int tt) {
        const int bf = tt & 1;
        *(uint4*)(&Kl[bf][krow][kd]) = make_uint4(
            cvt2(kpf[0].x,kpf[0].y), cvt2(kpf[0].z,kpf[0].w),
            cvt2(kpf[1].x,kpf[1].y), cvt2(kpf[1].z,kpf[1].w));
        *(uint4*)(&Kl[bf][krow][kd+8]) = make_uint4(
            cvt2(kpf[2].x,kpf[2].y), cvt2(kpf[2].z,kpf[2].w),
            cvt2(kpf[3].x,kpf[3].y), cvt2(kpf[3].z,kpf[3].w));
        #pragma unroll
        for (int ii = 0; ii < 4; ++ii) {
            Vt[bf][vd0+4*ii+0][vrow] = cvt1(vpf[ii].x);
            Vt[bf][vd0+4*ii+1][vrow] = cvt1(vpf[ii].y);
            Vt[bf][vd0+4*ii+2][vrow] = cvt1(vpf[ii].z);
            Vt[bf][vd0+4*ii+3][vrow] = cvt1(vpf[ii].w);
        }
    };

    #pragma unroll 1
    for (int pass = 0; pass < 2; ++pass) {
        const int qt = pass ? j : (15 - j);
        const int nt = 2*qt + 1;                 // staged kv tiles 0..nt
        const int dr = rg >> 1;                  // diagonal sub-tile parity for my rows
        const int my_tmax = 2*qt + ((dr == g) ? dr : dr - 1);
        const int diagw   = 2*qt + dr;           // tile needing the causal mask
        const int qcmp    = q31 + 32*(rg & 1);
        const int qrow    = qt*128 + rg*32 + q31;

        // ---- Q fragments (B operand of swapped QK^T), scale*log2e folded ----
        bf16x8 qf[4];
        {
            const float* qp = Qhead + (size_t)qrow * QSTR;
            #pragma unroll
            for (int ks = 0; ks < 4; ++ks) {
                const int d = ks*16 + h*8;
                const float4 x = *(const float4*)(qp + d);
                const float4 y = *(const float4*)(qp + d + 4);
                union { u32 u[4]; bf16x8 v; } t4;
                t4.u[0] = cvt2(x.x*QSCALE, x.y*QSCALE);
                t4.u[1] = cvt2(x.z*QSCALE, x.w*QSCALE);
                t4.u[2] = cvt2(y.x*QSCALE, y.y*QSCALE);
                t4.u[3] = cvt2(y.z*QSCALE, y.w*QSCALE);
                qf[ks] = t4.v;
            }
        }

        f32x16 oacc0, oacc1;   // O^T: [q=q31][dv = set*32 + (rg&3)+8*(rg>>2)+4h]
        #pragma unroll
        for (int i = 0; i < 16; ++i) { oacc0[i] = 0.f; oacc1[i] = 0.f; }
        float m_s = -1e30f, l_p = 0.f;

        // ---- prologue: g0 stages tile 0 + preloads tile 2; g1 preloads tile 1 ----
        if (g == 0) { ISSUE(0); WRITE(0); if (nt >= 2) ISSUE(2); }
        else        { ISSUE(1); }
        __syncthreads();

        for (int t = 0; t <= nt; ++t) {
            if ((t & 1) == g) {
                if (t <= my_tmax) {
                    const int bf = t & 1;
                    // ---- swapped QK^T (32x32x16) ----
                    f32x16 s0, s1;
                    #pragma unroll
                    for (int i = 0; i < 16; ++i) { s0[i] = 0.f; s1[i] = 0.f; }
                    __builtin_amdgcn_s_setprio(1);
                    #pragma unroll
                    for (int ks = 0; ks < 4; ++ks) {
                        bf16x8 k0 = *(const bf16x8*)(&Kl[bf][q31][ks*16 + h*8]);
                        bf16x8 k1 = *(const bf16x8*)(&Kl[bf][32 + q31][ks*16 + h*8]);
                        s0 = __builtin_amdgcn_mfma_f32_32x32x16_bf16(k0, qf[ks], s0, 0, 0, 0);
                        s1 = __builtin_amdgcn_mfma_f32_32x32x16_bf16(k1, qf[ks], s1, 0, 0, 0);
                    }
                    __builtin_amdgcn_s_setprio(0);

                    // ---- causal mask on this wave's diagonal tile ----
                    if (t == diagw) {
                        #pragma unroll
                        for (int rgi = 0; rgi < 16; ++rgi) {
                            const int kvl = (rgi & 3) + 8*(rgi >> 2) + 4*h;
                            if (kvl > qcmp)      s0[rgi] = -1e30f;
                            if (kvl + 32 > qcmp) s1[rgi] = -1e30f;
                        }
                    }

                    // ---- local 32-max (tree) ----
                    float mx[8];
                    #pragma unroll
                    for (int i = 0; i < 8; ++i)
                        mx[i] = fmaxf(fmaxf(s0[i], s0[i+8]), fmaxf(s1[i], s1[i+8]));
                    const float lmax = fmaxf(fmaxf(fmaxf(mx[0],mx[1]), fmaxf(mx[2],mx[3])),
                                             fmaxf(fmaxf(mx[4],mx[5]), fmaxf(mx[6],mx[7])));

                    // ---- T13 defer-max ----
                    if (!__all(lmax <= m_s + DEFER_THR)) {
                        float rmax = fmaxf(lmax, __shfl_xor(lmax, 32));
                        const float mnew = fmaxf(m_s, rmax);
                        const float cf   = __builtin_amdgcn_exp2f(m_s - mnew);
                        m_s = mnew;
                        l_p *= cf;
                        #pragma unroll
                        for (int i = 0; i < 16; ++i) { oacc0[i] *= cf; oacc1[i] *= cf; }
                    }

                    // ---- exp2 + partial sums ----
                    float ps0 = 0.f, ps1 = 0.f;
                    #pragma unroll
                    for (int rgi = 0; rgi < 16; ++rgi) {
                        const float p0 = __builtin_amdgcn_exp2f(s0[rgi] - m_s);
                        const float p1 = __builtin_amdgcn_exp2f(s1[rgi] - m_s);
                        s0[rgi] = p0; ps0 += p0;
                        s1[rgi] = p1; ps1 += p1;
                    }
                    l_p += ps0 + ps1;

                    // ---- T12: P -> B-operand in registers ----
                    u32 Aw[8], Bw[8];
                    #pragma unroll
                    for (int m = 0; m < 4; ++m) {
                        Aw[m]   = cvt2(s0[m*4+0], s0[m*4+1]);
                        Bw[m]   = cvt2(s0[m*4+2], s0[m*4+3]);
                        Aw[4+m] = cvt2(s1[m*4+0], s1[m*4+1]);
                        Bw[4+m] = cvt2(s1[m*4+2], s1[m*4+3]);
                    }

                    // ---- O^T += V^T P via permlane32_swap fragments ----
                    __builtin_amdgcn_s_setprio(1);
                    #pragma unroll
                    for (int c = 0; c < 4; ++c) {
                        u32 w0 = Aw[2*c], w2 = Aw[2*c+1];
                        u32 w1 = Bw[2*c], w3 = Bw[2*c+1];
                        asm("v_permlane32_swap_b32 %0, %1" : "+v"(w0), "+v"(w2));
                        asm("v_permlane32_swap_b32 %0, %1" : "+v"(w1), "+v"(w3));
                        union { u32 u[4]; bf16x8 v; } pu;
                        pu.u[0] = w0; pu.u[1] = w1; pu.u[2] = w2; pu.u[3] = w3;
                        bf16x8 v0 = *(const bf16x8*)(&Vt[bf][q31][c*16 + h*8]);
                        bf16x8 v1 = *(const bf16x8*)(&Vt[bf][32 + q31][c*16 + h*8]);
                        oacc0 = __builtin_amdgcn_mfma_f32_32x32x16_bf16(v0, pu.v, oacc0, 0, 0, 0);
                        oacc1 = __builtin_amdgcn_mfma_f32_32x32x16_bf16(v1, pu.v, oacc1, 0, 0, 0);
                    }
                    __builtin_amdgcn_s_setprio(0);
                }
            } else {
                // off-slot: stage my group's next tile, issue loads 2 slots ahead
                if (t + 1 <= nt) WRITE(t + 1);
                if (t + 3 <= nt) ISSUE(t + 3);
            }
            __syncthreads();
        }

        // ---- pass merge: combine even/odd kv partials (flash 2-way merge) ----
        l_p += __shfl_xor(l_p, 32);
        if (g == 1) {
            #pragma unroll
            for (int k2 = 0; k2 < 4; ++k2) {
                *(float4*)(&Mo[rg][q31][8*k2 + 4*h]) =
                    make_float4(oacc0[4*k2], oacc0[4*k2+1], oacc0[4*k2+2], oacc0[4*k2+3]);
                *(float4*)(&Mo[rg][q31][32 + 8*k2 + 4*h]) =
                    make_float4(oacc1[4*k2], oacc1[4*k2+1], oacc1[4*k2+2], oacc1[4*k2+3]);
            }
            if (h == 0) { Mm[rg][q31] = m_s; Ml[rg][q31] = l_p; }
        }
        __syncthreads();
        if (g == 0) {
            const float m1 = Mm[rg][q31], l1 = Ml[rg][q31];
            const float mn  = fmaxf(m_s, m1);
            const float a   = __builtin_amdgcn_exp2f(m_s - mn);
            const float bsc = __builtin_amdgcn_exp2f(m1 - mn);
            const float inv = 1.0f / (a*l_p + bsc*l1);
            const float ai = a*inv, bi = bsc*inv;
            float* ob = Ohead + (size_t)qrow * HD;
            #pragma unroll
            for (int k2 = 0; k2 < 4; ++k2) {
                const float4 p0 = *(const float4*)(&Mo[rg][q31][8*k2 + 4*h]);
                const float4 p1 = *(const float4*)(&Mo[rg][q31][32 + 8*k2 + 4*h]);
                float4 o;
                o.x = oacc0[4*k2+0]*ai + p0.x*bi;
                o.y = oacc0[4*k2+1]*ai + p0.y*bi;
                o.z = oacc0[4*k2+2]*ai + p0.z*bi;
                o.w = oacc0[4*k2+3]*ai + p0.w*bi;
                *(float4*)(ob + 8*k2 + 4*h) = o;
                o.x = oacc1[4*k2+0]*ai + p1.x*bi;
                o.y = oacc1[4*k2+1]*ai + p1.y*bi;
                o.z = oacc1[4*k2+2]*ai + p1.z*bi;
                o.w = oacc1[4*k2+3]*ai + p1.w*bi;
                *(float4*)(ob + 32 + 8*k2 + 4*h) = o;
            }
        }
    }
}

extern "C" void kernel_launch(void* const* d_in, const int* in_sizes, int n_in,
                              void* d_out, int out_size, void* d_ws, size_t ws_size,
                              hipStream_t stream) {
    const float* Q = (const float*)d_in[0];
    const float* K = (const float*)d_in[1];
    const float* V = (const float*)d_in[2];
    // d_in[3] (tril mask) computed analytically, never read.
    float* O = (float*)d_out;
    gqa_fwd_kernel<<<dim3(256), dim3(512), 0, stream>>>(Q, K, V, O);
}